// Round 1
// baseline (59.216 us; speedup 1.0000x reference)
//
#include <hip/hip_runtime.h>

#define E 1280
#define H 20
#define L 8192
#define D 64
#define CHUNK 256
#define NCHUNK (L / CHUNK)   // 32

// ---------------------------------------------------------------- K1: QKV GEMVs
// 3*E rows; one wave (64 lanes) per row; block = 256 = 4 rows.
__global__ void qkv_kernel(const float* __restrict__ hs,
                           const float* __restrict__ Wq, const float* __restrict__ bq,
                           const float* __restrict__ Wk,
                           const float* __restrict__ Wv, const float* __restrict__ bv,
                           float* __restrict__ qkv) {
    int row_global = blockIdx.x * 4 + (threadIdx.x >> 6);   // 0..3839
    int lane = threadIdx.x & 63;
    int mat = row_global / E;     // 0=q, 1=k, 2=v
    int row = row_global - mat * E;
    const float* W = (mat == 0) ? Wq : (mat == 1) ? Wk : Wv;
    const float4* Wrow = (const float4*)(W + (size_t)row * E);
    const float4* h4 = (const float4*)hs;
    float sum = 0.f;
#pragma unroll
    for (int i = 0; i < 5; ++i) {              // 320 float4 per row / 64 lanes
        int idx = lane + 64 * i;
        float4 w4 = Wrow[idx];
        float4 x4 = h4[idx];
        sum += w4.x * x4.x + w4.y * x4.y + w4.z * x4.z + w4.w * x4.w;
    }
#pragma unroll
    for (int off = 32; off > 0; off >>= 1) sum += __shfl_down(sum, off, 64);
    if (lane == 0) {
        float val;
        if (mat == 0)      val = (sum + bq[row]) * 0.125f;   // scale = 64^-0.5
        else if (mat == 1) val = sum;                        // k: no bias
        else               val = sum + bv[row];
        qkv[mat * E + row] = val;
    }
}

// ---------------------------------------------------------------- K2: K copy + scores
// grid = H*NCHUNK blocks of 256. Wave lane = 16*rr + cc; cc indexes d (4 floats),
// rr indexes row-within-group. Block processes 16 rows/iter.
__global__ void kpass_kernel(const float* __restrict__ kc, const float* __restrict__ qkv,
                             const int* __restrict__ pos_p,
                             float* __restrict__ out_k,
                             float* __restrict__ scores, float* __restrict__ chunk_max) {
    int h = blockIdx.x / NCHUNK;
    int c = blockIdx.x - h * NCHUNK;
    int pos = pos_p[0];
    int wave = threadIdx.x >> 6;
    int lane = threadIdx.x & 63;
    int rr = lane >> 4;
    int cc = lane & 15;
    float4 q4  = ((const float4*)qkv)[h * 16 + cc];
    float4 kn4 = ((const float4*)(qkv + E))[h * 16 + cc];
    const float* kbase = kc    + ((size_t)h * L + (size_t)c * CHUNK) * D;
    float*       obase = out_k + ((size_t)h * L + (size_t)c * CHUNK) * D;
    int l0 = c * CHUNK;
    float local_max = -INFINITY;
#pragma unroll 4
    for (int it = 0; it < CHUNK / 16; ++it) {
        int r = it * 16 + wave * 4 + rr;
        int l = l0 + r;
        float4 k4 = ((const float4*)(kbase + r * D))[cc];
        if (l == pos) k4 = kn4;
        ((float4*)(obase + r * D))[cc] = k4;
        float p = q4.x * k4.x + q4.y * k4.y + q4.z * k4.z + q4.w * k4.w;
        p += __shfl_xor(p, 1, 16);
        p += __shfl_xor(p, 2, 16);
        p += __shfl_xor(p, 4, 16);
        p += __shfl_xor(p, 8, 16);
        float s = (l <= pos) ? p : -INFINITY;
        if (cc == 0) scores[h * L + l] = s;
        local_max = fmaxf(local_max, s);
    }
#pragma unroll
    for (int off = 32; off > 0; off >>= 1)
        local_max = fmaxf(local_max, __shfl_down(local_max, off, 64));
    __shared__ float smax[4];
    if (lane == 0) smax[wave] = local_max;
    __syncthreads();
    if (threadIdx.x == 0)
        chunk_max[h * NCHUNK + c] = fmaxf(fmaxf(smax[0], smax[1]), fmaxf(smax[2], smax[3]));
}

// ---------------------------------------------------------------- K3: softmax per head
__global__ void softmax_kernel(float* __restrict__ scores, const float* __restrict__ chunk_max) {
    int h = blockIdx.x;
    int tid = threadIdx.x;          // 256 threads
    float m = -INFINITY;
    for (int i = 0; i < NCHUNK; ++i) m = fmaxf(m, chunk_max[h * NCHUNK + i]);
    float* srow = scores + (size_t)h * L;
    float lsum = 0.f;
    for (int i = tid; i < L; i += 256) {
        float e = expf(srow[i] - m);   // masked (-inf) -> 0
        srow[i] = e;
        lsum += e;
    }
#pragma unroll
    for (int off = 32; off > 0; off >>= 1) lsum += __shfl_down(lsum, off, 64);
    __shared__ float ssum[4];
    int wave = tid >> 6, lane = tid & 63;
    if (lane == 0) ssum[wave] = lsum;
    __syncthreads();
    float denom = ssum[0] + ssum[1] + ssum[2] + ssum[3];
    float inv = 1.f / denom;
    for (int i = tid; i < L; i += 256) srow[i] *= inv;
}

// ---------------------------------------------------------------- K4: V copy + PV partials
__global__ void vpass_kernel(const float* __restrict__ vc, const float* __restrict__ qkv,
                             const int* __restrict__ pos_p, const float* __restrict__ weights,
                             float* __restrict__ out_v, float* __restrict__ o_part) {
    int h = blockIdx.x / NCHUNK;
    int c = blockIdx.x - h * NCHUNK;
    int pos = pos_p[0];
    int wave = threadIdx.x >> 6;
    int lane = threadIdx.x & 63;
    int rr = lane >> 4;
    int cc = lane & 15;
    float4 vn4 = ((const float4*)(qkv + 2 * E))[h * 16 + cc];
    const float* vbase = vc    + ((size_t)h * L + (size_t)c * CHUNK) * D;
    float*       obase = out_v + ((size_t)h * L + (size_t)c * CHUNK) * D;
    int l0 = c * CHUNK;
    float4 acc = {0.f, 0.f, 0.f, 0.f};
#pragma unroll 4
    for (int it = 0; it < CHUNK / 16; ++it) {
        int r = it * 16 + wave * 4 + rr;
        int l = l0 + r;
        float4 v4 = ((const float4*)(vbase + r * D))[cc];
        if (l == pos) v4 = vn4;
        ((float4*)(obase + r * D))[cc] = v4;
        float w = weights[h * L + l];
        acc.x += w * v4.x; acc.y += w * v4.y; acc.z += w * v4.z; acc.w += w * v4.w;
    }
    // reduce across rr groups (lanes ^16, ^32)
    acc.x += __shfl_xor(acc.x, 16, 64); acc.y += __shfl_xor(acc.y, 16, 64);
    acc.z += __shfl_xor(acc.z, 16, 64); acc.w += __shfl_xor(acc.w, 16, 64);
    acc.x += __shfl_xor(acc.x, 32, 64); acc.y += __shfl_xor(acc.y, 32, 64);
    acc.z += __shfl_xor(acc.z, 32, 64); acc.w += __shfl_xor(acc.w, 32, 64);
    if (rr == 0) {
        float* op = o_part + (((size_t)h * NCHUNK + c) * 4 + wave) * D;
        ((float4*)op)[cc] = acc;
    }
}

// ---------------------------------------------------------------- K5: reduce partials
__global__ void reduce_kernel(const float* __restrict__ o_part, float* __restrict__ attn_out) {
    int h = blockIdx.x;
    int d = threadIdx.x;            // 64 threads
    float s = 0.f;
    const float* base = o_part + (size_t)h * NCHUNK * 4 * D;
    for (int p = 0; p < NCHUNK * 4; ++p) s += base[p * D + d];
    attn_out[h * D + d] = s;
}

// ---------------------------------------------------------------- K6: output GEMV
__global__ void ogemv_kernel(const float* __restrict__ attn_out, const float* __restrict__ Wo,
                             const float* __restrict__ bo, float* __restrict__ out) {
    int row = blockIdx.x * 4 + (threadIdx.x >> 6);
    int lane = threadIdx.x & 63;
    const float4* Wrow = (const float4*)(Wo + (size_t)row * E);
    const float4* x4 = (const float4*)attn_out;
    float sum = 0.f;
#pragma unroll
    for (int i = 0; i < 5; ++i) {
        int idx = lane + 64 * i;
        float4 w4 = Wrow[idx];
        float4 a4 = x4[idx];
        sum += w4.x * a4.x + w4.y * a4.y + w4.z * a4.z + w4.w * a4.w;
    }
#pragma unroll
    for (int off = 32; off > 0; off >>= 1) sum += __shfl_down(sum, off, 64);
    if (lane == 0) out[row] = sum + bo[row];
}

extern "C" void kernel_launch(void* const* d_in, const int* in_sizes, int n_in,
                              void* d_out, int out_size, void* d_ws, size_t ws_size,
                              hipStream_t stream) {
    const float* hs  = (const float*)d_in[0];
    const int*   pos = (const int*)d_in[1];    // little-endian: low word of int64 ok
    const float* kc  = (const float*)d_in[2];
    const float* vc  = (const float*)d_in[3];
    const float* Wq  = (const float*)d_in[4];
    const float* bq  = (const float*)d_in[5];
    const float* Wk  = (const float*)d_in[6];
    const float* Wv  = (const float*)d_in[7];
    const float* bv  = (const float*)d_in[8];
    const float* Wo  = (const float*)d_in[9];
    const float* bo  = (const float*)d_in[10];

    float* out   = (float*)d_out;                 // [0 : E)        attention output
    float* out_k = out + E;                       // new_k_cache  (H*L*D)
    float* out_v = out_k + (size_t)H * L * D;     // new_v_cache

    float* ws       = (float*)d_ws;
    float* qkv      = ws;                          // 3*E
    float* scores   = qkv + 3 * E;                 // H*L
    float* cmax     = scores + (size_t)H * L;      // H*NCHUNK
    float* o_part   = cmax + H * NCHUNK;           // H*NCHUNK*4*D
    float* attn_out = o_part + (size_t)H * NCHUNK * 4 * D;  // E

    qkv_kernel<<<3 * E / 4, 256, 0, stream>>>(hs, Wq, bq, Wk, Wv, bv, qkv);
    kpass_kernel<<<H * NCHUNK, 256, 0, stream>>>(kc, qkv, pos, out_k, scores, cmax);
    softmax_kernel<<<H, 256, 0, stream>>>(scores, cmax);
    vpass_kernel<<<H * NCHUNK, 256, 0, stream>>>(vc, qkv, pos, scores, out_v, o_part);
    reduce_kernel<<<H, 64, 0, stream>>>(o_part, attn_out);
    ogemv_kernel<<<E / 4, 256, 0, stream>>>(attn_out, Wo, bo, out);
}

// Round 2
// 42.620 us; speedup vs baseline: 1.3894x; 1.3894x over previous
//
#include <hip/hip_runtime.h>

#define E 1280
#define H 20
#define L 8192
#define D 64
#define CHUNK 256
#define NCHUNK (L / CHUNK)   // 32

// ---------------------------------------------------------------- K1: QKV GEMVs
// 3*E rows; one wave (64 lanes) per row; block = 256 = 4 rows.
__global__ void qkv_kernel(const float* __restrict__ hs,
                           const float* __restrict__ Wq, const float* __restrict__ bq,
                           const float* __restrict__ Wk,
                           const float* __restrict__ Wv, const float* __restrict__ bv,
                           float* __restrict__ qkv) {
    int row_global = blockIdx.x * 4 + (threadIdx.x >> 6);   // 0..3839
    int lane = threadIdx.x & 63;
    int mat = row_global / E;     // 0=q, 1=k, 2=v
    int row = row_global - mat * E;
    const float* W = (mat == 0) ? Wq : (mat == 1) ? Wk : Wv;
    const float4* Wrow = (const float4*)(W + (size_t)row * E);
    const float4* h4 = (const float4*)hs;
    float sum = 0.f;
#pragma unroll
    for (int i = 0; i < 5; ++i) {              // 320 float4 per row / 64 lanes
        int idx = lane + 64 * i;
        float4 w4 = Wrow[idx];
        float4 x4 = h4[idx];
        sum += w4.x * x4.x + w4.y * x4.y + w4.z * x4.z + w4.w * x4.w;
    }
#pragma unroll
    for (int off = 32; off > 0; off >>= 1) sum += __shfl_down(sum, off, 64);
    if (lane == 0) {
        float val;
        if (mat == 0)      val = (sum + bq[row]) * 0.125f;   // scale = 64^-0.5
        else if (mat == 1) val = sum;                        // k: no bias
        else               val = sum + bv[row];
        qkv[mat * E + row] = val;
    }
}

// ---------------------------------------------------------------- K2: fused K+V pass
// grid = H*NCHUNK blocks of 256 (4 waves). Lane layout: rr = lane>>4 (row in
// group of 4), cc = lane&15 (16 lanes x float4 cover D=64).
// Pass 1: read K chunk (sub k_new at pos), write new_k_cache, scores -> LDS,
//         block max. Pass 2: read V chunk (sub v_new), write new_v_cache,
//         accumulate exp(s-m)*V and sum(exp). Emit per-chunk m, sum, o[64].
__global__ void kv_kernel(const float* __restrict__ kc, const float* __restrict__ vc,
                          const float* __restrict__ qkv, const int* __restrict__ pos_p,
                          float* __restrict__ out_k, float* __restrict__ out_v,
                          float* __restrict__ cmax, float* __restrict__ csum,
                          float* __restrict__ o_part) {
    int h = blockIdx.x / NCHUNK;
    int c = blockIdx.x - h * NCHUNK;
    int pos = pos_p[0];
    int wave = threadIdx.x >> 6;
    int lane = threadIdx.x & 63;
    int rr = lane >> 4;
    int cc = lane & 15;

    __shared__ float s_lds[CHUNK];
    __shared__ float sacc[4][D];
    __shared__ float smax[4];
    __shared__ float spsum[4];

    float4 q4  = ((const float4*)qkv)[h * 16 + cc];
    float4 kn4 = ((const float4*)(qkv + E))[h * 16 + cc];
    float4 vn4 = ((const float4*)(qkv + 2 * E))[h * 16 + cc];

    size_t base = ((size_t)h * L + (size_t)c * CHUNK) * D;
    const float* kbase = kc + base;
    const float* vbase = vc + base;
    float* okbase = out_k + base;
    float* ovbase = out_v + base;
    int l0 = c * CHUNK;

    // ---- pass 1: K copy + scores
    float lmax = -INFINITY;
#pragma unroll 4
    for (int it = 0; it < CHUNK / 16; ++it) {
        int r = it * 16 + wave * 4 + rr;
        int l = l0 + r;
        float4 k4 = ((const float4*)(kbase + r * D))[cc];
        if (l == pos) k4 = kn4;
        ((float4*)(okbase + r * D))[cc] = k4;
        float p = q4.x * k4.x + q4.y * k4.y + q4.z * k4.z + q4.w * k4.w;
        p += __shfl_xor(p, 1, 16);
        p += __shfl_xor(p, 2, 16);
        p += __shfl_xor(p, 4, 16);
        p += __shfl_xor(p, 8, 16);
        float s = (l <= pos) ? p : -INFINITY;
        if (cc == 0) s_lds[r] = s;
        lmax = fmaxf(lmax, s);
    }
#pragma unroll
    for (int off = 32; off > 0; off >>= 1)
        lmax = fmaxf(lmax, __shfl_xor(lmax, off, 64));
    if (lane == 0) smax[wave] = lmax;
    __syncthreads();
    float m = fmaxf(fmaxf(smax[0], smax[1]), fmaxf(smax[2], smax[3]));

    // ---- pass 2: V copy + weighted accumulate (unnormalized, chunk-local max)
    float4 acc = {0.f, 0.f, 0.f, 0.f};
    float psum = 0.f;
#pragma unroll 4
    for (int it = 0; it < CHUNK / 16; ++it) {
        int r = it * 16 + wave * 4 + rr;
        int l = l0 + r;
        float4 v4 = ((const float4*)(vbase + r * D))[cc];
        if (l == pos) v4 = vn4;
        ((float4*)(ovbase + r * D))[cc] = v4;
        float p = (l <= pos) ? __expf(s_lds[r] - m) : 0.f;
        acc.x += p * v4.x; acc.y += p * v4.y; acc.z += p * v4.z; acc.w += p * v4.w;
        if (cc == 0) psum += p;
    }
    // reduce across rr groups (lanes ^16, ^32): cc lanes keep their d-slice
    acc.x += __shfl_xor(acc.x, 16, 64); acc.y += __shfl_xor(acc.y, 16, 64);
    acc.z += __shfl_xor(acc.z, 16, 64); acc.w += __shfl_xor(acc.w, 16, 64);
    acc.x += __shfl_xor(acc.x, 32, 64); acc.y += __shfl_xor(acc.y, 32, 64);
    acc.z += __shfl_xor(acc.z, 32, 64); acc.w += __shfl_xor(acc.w, 32, 64);
    psum += __shfl_xor(psum, 16, 64);
    psum += __shfl_xor(psum, 32, 64);
    if (rr == 0) {
        ((float4*)&sacc[wave][cc * 4])[0] = acc;
        if (cc == 0) spsum[wave] = psum;
    }
    __syncthreads();
    if (threadIdx.x < D) {            // wave 0: final cross-wave sum + emit
        int d = threadIdx.x;
        float o = sacc[0][d] + sacc[1][d] + sacc[2][d] + sacc[3][d];
        o_part[((size_t)h * NCHUNK + c) * D + d] = o;
        if (d == 0) {
            cmax[h * NCHUNK + c] = m;
            csum[h * NCHUNK + c] = spsum[0] + spsum[1] + spsum[2] + spsum[3];
        }
    }
}

// ---------------------------------------------------------------- K3: cross-chunk combine
__global__ void combine_kernel(const float* __restrict__ cmax, const float* __restrict__ csum,
                               const float* __restrict__ o_part, float* __restrict__ attn_out) {
    int h = blockIdx.x;
    int d = threadIdx.x;              // 64 threads
    float m = -INFINITY;
#pragma unroll
    for (int c = 0; c < NCHUNK; ++c) m = fmaxf(m, cmax[h * NCHUNK + c]);
    float denom = 0.f, o = 0.f;
#pragma unroll 4
    for (int c = 0; c < NCHUNK; ++c) {
        float mc = cmax[h * NCHUNK + c];
        float sc = (mc > -1e30f) ? __expf(mc - m) : 0.f;
        denom += csum[h * NCHUNK + c] * sc;
        o += o_part[((size_t)h * NCHUNK + c) * D + d] * sc;
    }
    attn_out[h * D + d] = o / denom;
}

// ---------------------------------------------------------------- K4: output GEMV
__global__ void ogemv_kernel(const float* __restrict__ attn_out, const float* __restrict__ Wo,
                             const float* __restrict__ bo, float* __restrict__ out) {
    int row = blockIdx.x * 4 + (threadIdx.x >> 6);
    int lane = threadIdx.x & 63;
    const float4* Wrow = (const float4*)(Wo + (size_t)row * E);
    const float4* x4 = (const float4*)attn_out;
    float sum = 0.f;
#pragma unroll
    for (int i = 0; i < 5; ++i) {
        int idx = lane + 64 * i;
        float4 w4 = Wrow[idx];
        float4 a4 = x4[idx];
        sum += w4.x * a4.x + w4.y * a4.y + w4.z * a4.z + w4.w * a4.w;
    }
#pragma unroll
    for (int off = 32; off > 0; off >>= 1) sum += __shfl_down(sum, off, 64);
    if (lane == 0) out[row] = sum + bo[row];
}

extern "C" void kernel_launch(void* const* d_in, const int* in_sizes, int n_in,
                              void* d_out, int out_size, void* d_ws, size_t ws_size,
                              hipStream_t stream) {
    const float* hs  = (const float*)d_in[0];
    const int*   pos = (const int*)d_in[1];    // int64 little-endian: low word ok (0<=pos<8192)
    const float* kc  = (const float*)d_in[2];
    const float* vc  = (const float*)d_in[3];
    const float* Wq  = (const float*)d_in[4];
    const float* bq  = (const float*)d_in[5];
    const float* Wk  = (const float*)d_in[6];
    const float* Wv  = (const float*)d_in[7];
    const float* bv  = (const float*)d_in[8];
    const float* Wo  = (const float*)d_in[9];
    const float* bo  = (const float*)d_in[10];

    float* out   = (float*)d_out;                 // [0 : E)        attention output
    float* out_k = out + E;                       // new_k_cache  (H*L*D)
    float* out_v = out_k + (size_t)H * L * D;     // new_v_cache

    float* ws       = (float*)d_ws;
    float* qkv      = ws;                             // 3*E
    float* cmax     = qkv + 3 * E;                    // H*NCHUNK
    float* csum     = cmax + H * NCHUNK;              // H*NCHUNK
    float* o_part   = csum + H * NCHUNK;              // H*NCHUNK*D
    float* attn_out = o_part + (size_t)H * NCHUNK * D;  // E

    qkv_kernel<<<3 * E / 4, 256, 0, stream>>>(hs, Wq, bq, Wk, Wv, bv, qkv);
    kv_kernel<<<H * NCHUNK, 256, 0, stream>>>(kc, vc, qkv, pos, out_k, out_v,
                                              cmax, csum, o_part);
    combine_kernel<<<H, 64, 0, stream>>>(cmax, csum, o_part, attn_out);
    ogemv_kernel<<<E / 4, 256, 0, stream>>>(attn_out, Wo, bo, out);
}